// Round 9
// baseline (8405.070 us; speedup 1.0000x reference)
//
#include <hip/hip_runtime.h>
#include <hip/hip_bf16.h>

// ---------------------------------------------------------------------------
// Sophie on MI355X, round 9.
// k-projection eliminated (logit_r = A_r·m + cq, m = wk^T q precomputed).
// Dispatch p (577 blocks): 512 gate tiles (128x128, LSTM fused), 64 v-blocks
// (v-GEMM + logits + partial softmax-weighted sums; last-done writes out[p]),
// 1 target block (target LSTM matvec -> ht[p+1], q[p+1], m[p+1]).
// XCD-affine mapping end-to-end so A/An/co slices stay per-XCD L2-resident.
// ---------------------------------------------------------------------------

typedef __bf16 bf16x8 __attribute__((ext_vector_type(8)));
typedef float  f32x4  __attribute__((ext_vector_type(4)));

#define KD 512

__device__ __forceinline__ void gl_lds16(const void* g, void* l) {
  __builtin_amdgcn_global_load_lds(
      (const __attribute__((address_space(1))) void*)g,
      (__attribute__((address_space(3))) void*)l, 16, 0, 0);
}
__device__ __forceinline__ float sigm(float x) {
  return __builtin_amdgcn_rcpf(1.f + __expf(-x));
}
__device__ __forceinline__ float tanh_f(float x) {
  return 2.f * __builtin_amdgcn_rcpf(1.f + __expf(-2.f * x)) - 1.f;
}
__device__ __forceinline__ float sel4(f32x4 v, int i) {
  float a = (i & 1) ? v[1] : v[0];
  float b = (i & 1) ? v[3] : v[2];
  return (i & 2) ? b : a;
}
__device__ __forceinline__ float pick(int m, float o0, float o1, float o2, float o3) {
  float a = (m & 1) ? o1 : o0;
  float b = (m & 1) ? o3 : o2;
  return (m & 2) ? b : a;
}

struct SP {
  const unsigned short* Wp;        // [160 ntg][64 kg][16 nn][8 j] bf16: gates|wv
  unsigned short* A0; unsigned short* A1;   // [4096][512] bf16 others' h
  float* co;                       // [4096][512] others' c
  float* ct;                       // [512] target c
  float* ht;                       // [65][512] target h per step
  const float4* bs4; const float4* w04; const float4* w14;
  const unsigned short* wqT;       // bf16 [i][j] = wq[j][i]
  const unsigned short* wkB;       // bf16 [j][i] = wk[j][i]
  const float* bq; const float* bk; const float* bv;
  const float* others; const float* target;
  const float* scene; const float* out_w; const float* out_b;
  float* part;                     // [64][520]
  unsigned int* cnt;
  float* out;
  float* m0; float* m1;            // [513]: m[512] + cq ; parity by step
};

// ---------------------------------------------------------------------------
// Gate tile 128x128 (rows < 4096 only): gates (col=4u+g) -> fused LSTM.
// ---------------------------------------------------------------------------
__device__ void do_gate(const SP& P, int p, int bm, int bn, char* smem)
{
  const int tid = threadIdx.x, wave = tid >> 6, lane = tid & 63;
  const unsigned short* A = (p & 1) ? P.A1 : P.A0;
  __bf16* An = (__bf16*)((p & 1) ? P.A0 : P.A1);
  const int tin = (p + 1 < 31) ? (p + 1) : 31;
  const float* op = P.others + (size_t)tin * 8192;

  const int m0 = bm * 128;
  const int l15 = lane & 15, lq = lane >> 4;

  int aRow[4], aOff[4], ldsOff[4];
#pragma unroll
  for (int j = 0; j < 4; ++j) {
    int chunk = j * 4 + wave;
    int r = chunk * 8 + (lane >> 3), ch = lane & 7;
    aRow[j]   = m0 + r;
    aOff[j]   = (ch ^ (r & 7)) * 8;
    ldsOff[j] = chunk * 1024;
  }
  const unsigned short* bBase =
      P.Wp + (size_t)(bn * 8 + wave * 2) * 8192 + lq * 128 + l15 * 8;

  f32x4 acc[8][2];
#pragma unroll
  for (int i = 0; i < 8; ++i) { acc[i][0] = f32x4{0,0,0,0}; acc[i][1] = f32x4{0,0,0,0}; }

#pragma unroll
  for (int j = 0; j < 4; ++j)
    gl_lds16(A + (size_t)aRow[j] * KD + aOff[j], smem + ldsOff[j]);
  __syncthreads();

  for (int it = 0; it < 8; ++it) {
    const char* buf = smem + (it & 1) * 16384;
    if (it < 7) {
      const int k1 = (it + 1) * 64;
      char* nbuf = smem + ((it + 1) & 1) * 16384;
#pragma unroll
      for (int j = 0; j < 4; ++j)
        gl_lds16(A + (size_t)aRow[j] * KD + k1 + aOff[j], nbuf + ldsOff[j]);
    }
#pragma unroll
    for (int c = 0; c < 2; ++c) {
      bf16x8 bC[2];
#pragma unroll
      for (int nt = 0; nt < 2; ++nt)
        bC[nt] = *(const bf16x8*)(bBase + nt * 8192 + it * 1024 + c * 512);
      bf16x8 af[8];
#pragma unroll
      for (int mt = 0; mt < 8; ++mt) {
        int row = mt * 16 + l15;
        int ch16 = (c * 4 + lq) ^ (row & 7);
        af[mt] = *(const bf16x8*)(buf + row * 128 + ch16 * 16);
      }
#pragma unroll
      for (int mt = 0; mt < 8; ++mt)
#pragma unroll
        for (int nt = 0; nt < 2; ++nt)
          acc[mt][nt] = __builtin_amdgcn_mfma_f32_16x16x32_bf16(
              af[mt], bC[nt], acc[mt][nt], 0, 0, 0);
    }
    __syncthreads();
  }

  const int rq = lq * 4;
  const int rho = lane & 3, usel = (lane >> 2) & 3;
  const int u0 = bn * 32 + wave * 8;
  float4 bsv[2], w0v[2], w1v[2];
  int uu[2];
#pragma unroll
  for (int nt = 0; nt < 2; ++nt) {
    uu[nt]  = u0 + nt * 4 + usel;
    bsv[nt] = P.bs4[uu[nt]];
    w0v[nt] = P.w04[uu[nt]];
    w1v[nt] = P.w14[uu[nt]];
  }
#pragma unroll
  for (int mt = 0; mt < 8; ++mt) {
    int row = m0 + mt * 16 + rq + rho;
    float x0 = op[2 * row], x1 = op[2 * row + 1];
#pragma unroll
    for (int nt = 0; nt < 2; ++nt) {
      f32x4 v = acc[mt][nt];
      float own = sel4(v, rho);
      float r1  = __shfl_xor(sel4(v, rho ^ 1), 1, 64);
      float r2  = __shfl_xor(sel4(v, rho ^ 2), 2, 64);
      float r3  = __shfl_xor(sel4(v, rho ^ 3), 3, 64);
      float g0 = pick(rho,     own, r1, r2, r3);
      float g1 = pick(rho ^ 1, own, r1, r2, r3);
      float g2 = pick(rho ^ 2, own, r1, r2, r3);
      float g3 = pick(rho ^ 3, own, r1, r2, r3);
      float4 bs = bsv[nt], w0 = w0v[nt], w1 = w1v[nt];
      float p0 = g0 + bs.x + w0.x * x0 + w1.x * x1;
      float p1 = g1 + bs.y + w0.y * x0 + w1.y * x1;
      float p2 = g2 + bs.z + w0.z * x0 + w1.z * x1;
      float p3 = g3 + bs.w + w0.w * x0 + w1.w * x1;
      int u = uu[nt];
      size_t ci = (size_t)row * 512 + u;
      float c_old = P.co[ci];
      float ii = sigm(p0), ff = sigm(p1), gg = tanh_f(p2), oo = sigm(p3);
      float cn = ff * c_old + ii * gg;
      float h  = oo * tanh_f(cn);
      P.co[ci] = cn;
      An[ci] = (__bf16)h;
    }
  }
}

// ---------------------------------------------------------------------------
// v-block vb (64 rows x 512 v-cols): v-GEMM + fused logits (A_r·m + cq) +
// partial e·v sums; last-done block finalizes out[p]. m precomputed.
// smem: [0,16384) A dbuf | mf 2KB @16384 | ef 256B @18432 | red @18688 |
//       red2 @19712 | sOld @20736
// ---------------------------------------------------------------------------
__device__ void do_v(const SP& P, int p, int vb, char* smem)
{
  float* mf   = (float*)(smem + 16384);
  float* ef   = (float*)(smem + 18432);
  float* red  = (float*)(smem + 18688);
  float* red2 = (float*)(smem + 19712);
  unsigned int* sOldp = (unsigned int*)(smem + 20736);
  const int t = threadIdx.x, wave = t >> 6, lane = t & 63;
  const unsigned short* A = (p & 1) ? P.A1 : P.A0;
  const float* mq = (p & 1) ? P.m1 : P.m0;
  const float* ht = P.ht + (size_t)p * 512;
  const float cq = mq[512];

  const int l15 = lane & 15, lq = lane >> 4;
  const int m0r = vb * 64;
  int aRow[2], aOff[2], ldsOff[2];
#pragma unroll
  for (int j = 0; j < 2; ++j) {
    int chunk = wave * 2 + j;
    int r = chunk * 8 + (lane >> 3), ch = lane & 7;
    aRow[j]   = m0r + r;
    aOff[j]   = (ch ^ (r & 7)) * 8;
    ldsOff[j] = chunk * 1024;
  }
  const unsigned short* bBase =
      P.Wp + (size_t)(128 + wave * 8) * 8192 + lq * 128 + l15 * 8;

  f32x4 acc[4][8];
#pragma unroll
  for (int i = 0; i < 4; ++i)
#pragma unroll
    for (int j = 0; j < 8; ++j) acc[i][j] = f32x4{0.f, 0.f, 0.f, 0.f};
  float lp[4] = {0.f, 0.f, 0.f, 0.f};

  for (int c = t; c < 512; c += 256) mf[c] = mq[c];
#pragma unroll
  for (int j = 0; j < 2; ++j)
    gl_lds16(A + (size_t)aRow[j] * KD + aOff[j], smem + ldsOff[j]);
  __syncthreads();

  for (int it = 0; it < 8; ++it) {
    const char* buf = smem + (it & 1) * 8192;
    if (it < 7) {
      const int k1 = (it + 1) * 64;
      char* nbuf = smem + ((it + 1) & 1) * 8192;
#pragma unroll
      for (int j = 0; j < 2; ++j)
        gl_lds16(A + (size_t)aRow[j] * KD + k1 + aOff[j], nbuf + ldsOff[j]);
    }
#pragma unroll
    for (int c = 0; c < 2; ++c) {
      bf16x8 bC[8];
#pragma unroll
      for (int nt = 0; nt < 8; ++nt)
        bC[nt] = *(const bf16x8*)(bBase + nt * 8192 + it * 1024 + c * 512);
      bf16x8 af[4];
#pragma unroll
      for (int mt = 0; mt < 4; ++mt) {
        int row = mt * 16 + l15;
        int ch16 = (c * 4 + lq) ^ (row & 7);
        af[mt] = *(const bf16x8*)(buf + row * 128 + ch16 * 16);
      }
      const float* mseg = mf + it * 64 + c * 32 + lq * 8;
#pragma unroll
      for (int mt = 0; mt < 4; ++mt)
#pragma unroll
        for (int j = 0; j < 8; ++j)
          lp[mt] += (float)af[mt][j] * mseg[j];
#pragma unroll
      for (int mt = 0; mt < 4; ++mt)
#pragma unroll
        for (int nt = 0; nt < 8; ++nt)
          acc[mt][nt] = __builtin_amdgcn_mfma_f32_16x16x32_bf16(
              af[mt], bC[nt], acc[mt][nt], 0, 0, 0);
    }
    __syncthreads();
  }

  // logits -> e
  float e[4];
#pragma unroll
  for (int mt = 0; mt < 4; ++mt) {
    lp[mt] += __shfl_xor(lp[mt], 16, 64);
    lp[mt] += __shfl_xor(lp[mt], 32, 64);
    e[mt] = __expf((lp[mt] + cq) * 0.04419417382415922f);
    ef[mt * 16 + l15] = e[mt];
  }
  float de = e[0] + e[1] + e[2] + e[3];
#pragma unroll
  for (int msk = 1; msk <= 8; msk <<= 1) de += __shfl_xor(de, msk, 64);
  __syncthreads();

  // social partials
  const int rq = lq * 4;
  float s[8] = {0,0,0,0,0,0,0,0};
#pragma unroll
  for (int mt = 0; mt < 4; ++mt)
#pragma unroll
    for (int r = 0; r < 4; ++r) {
      float ee = ef[mt * 16 + rq + r];
#pragma unroll
      for (int nt = 0; nt < 8; ++nt) s[nt] += ee * acc[mt][nt][r];
    }
#pragma unroll
  for (int nt = 0; nt < 8; ++nt) {
    s[nt] += __shfl_xor(s[nt], 16, 64);
    s[nt] += __shfl_xor(s[nt], 32, 64);
  }
  if (lq == 0) {
#pragma unroll
    for (int nt = 0; nt < 8; ++nt)
      P.part[vb * 520 + wave * 128 + nt * 16 + l15] = s[nt];
  }
  if (t == 0) P.part[vb * 520 + 512] = de;

  __threadfence();
  __syncthreads();
  if (t == 0) *sOldp = atomicAdd(P.cnt, 1u);
  __syncthreads();
  if (*sOldp == 63) {
    __threadfence();
    float s0 = 0.f, s1 = 0.f, se = 0.f;
    for (int b2 = 0; b2 < 64; ++b2) {
      s0 += P.part[b2 * 520 + t];
      s1 += P.part[b2 * 520 + 256 + t];
      se += P.part[b2 * 520 + 512];
    }
    float inv = 1.f / se;
    float va  = ht[t]       + s0 * inv + P.bv[t]       + P.scene[t];
    float vb2 = ht[t + 256] + s1 * inv + P.bv[t + 256] + P.scene[t + 256];
    red[t]  = va * P.out_w[t]       + vb2 * P.out_w[t + 256];
    red2[t] = va * P.out_w[512 + t] + vb2 * P.out_w[768 + t];
    __syncthreads();
    for (int st = 128; st > 0; st >>= 1) {
      if (t < st) { red[t] += red[t + st]; red2[t] += red2[t + st]; }
      __syncthreads();
    }
    if (t == 0) {
      P.out[2 * p]     = red[0]  + P.out_b[0];
      P.out[2 * p + 1] = red2[0] + P.out_b[1];
      *P.cnt = 0;
    }
  }
}

// ---------------------------------------------------------------------------
// Target block: target-row LSTM matvec -> ht[p+1], then q[p+1], m[p+1], cq.
// ---------------------------------------------------------------------------
__device__ void do_target(const SP& P, int p, char* smem)
{
  float* hs  = (float*)smem;             // 512
  float* hn  = (float*)(smem + 2048);    // 512
  float* qs  = (float*)(smem + 4096);    // 512
  float* red = (float*)(smem + 6144);    // 256
  const int t = threadIdx.x;
  const float* ht = P.ht + (size_t)p * 512;
  for (int c = t; c < 512; c += 256) hs[c] = ht[c];
  __syncthreads();

  const int tc = (p + 1 < 63) ? (p + 1) : 63;
  const float x0 = P.target[2 * tc], x1 = P.target[2 * tc + 1];

  // gates for cols n = t*8 .. t*8+7 (units 2t, 2t+1 complete)
  float pre[8];
#pragma unroll
  for (int o = 0; o < 8; ++o) pre[o] = 0.f;
  {
    const unsigned short* wrow = P.Wp + (size_t)(t >> 1) * 8192 + (t & 1) * 64;
    for (int kg = 0; kg < 64; ++kg) {
      const unsigned short* w8 = wrow + kg * 128;
      const float* h8 = hs + kg * 8;
#pragma unroll
      for (int o = 0; o < 8; ++o) {
        bf16x8 w = *(const bf16x8*)(w8 + o * 8);
#pragma unroll
        for (int j = 0; j < 8; ++j) pre[o] += (float)w[j] * h8[j];
      }
    }
  }
#pragma unroll
  for (int half = 0; half < 2; ++half) {
    int u = 2 * t + half;
    float4 bs = P.bs4[u], w0 = P.w04[u], w1 = P.w14[u];
    float p0 = pre[half * 4 + 0] + bs.x + w0.x * x0 + w1.x * x1;
    float p1 = pre[half * 4 + 1] + bs.y + w0.y * x0 + w1.y * x1;
    float p2 = pre[half * 4 + 2] + bs.z + w0.z * x0 + w1.z * x1;
    float p3 = pre[half * 4 + 3] + bs.w + w0.w * x0 + w1.w * x1;
    float c_old = P.ct[u];
    float ii = sigm(p0), ff = sigm(p1), gg = tanh_f(p2), oo = sigm(p3);
    float cn = ff * c_old + ii * gg;
    float h  = oo * tanh_f(cn);
    P.ct[u] = cn;
    hn[u] = h;
    P.ht[(size_t)(p + 1) * 512 + u] = h;
  }
  __syncthreads();

  // q = hn @ wq.T + bq
  float q0 = P.bq[t], q1 = P.bq[t + 256];
  for (int i = 0; i < 512; ++i) {
    float h = hn[i];
    q0 += h * (float)(*(const __bf16*)&P.wqT[i * 512 + t]);
    q1 += h * (float)(*(const __bf16*)&P.wqT[i * 512 + t + 256]);
  }
  qs[t] = q0; qs[t + 256] = q1;
  red[t] = q0 * P.bk[t] + q1 * P.bk[t + 256];
  __syncthreads();

  // m = wk^T q
  float m0 = 0.f, m1 = 0.f;
  for (int j = 0; j < 512; ++j) {
    float qq = qs[j];
    m0 += qq * (float)(*(const __bf16*)&P.wkB[j * 512 + t]);
    m1 += qq * (float)(*(const __bf16*)&P.wkB[j * 512 + t + 256]);
  }
  float* mqn = (p & 1) ? P.m0 : P.m1;    // parity (p+1)&1
  mqn[t] = m0; mqn[t + 256] = m1;
  for (int st = 128; st > 0; st >>= 1) {
    if (t < st) red[t] += red[t + st];
    __syncthreads();
  }
  if (t == 0) mqn[512] = red[0];
}

// ---------------------------------------------------------------------------
__global__ __launch_bounds__(256, 2) void step_kernel(SP P, int p)
{
  __shared__ __align__(16) char smem[36864];
  const int b = blockIdx.x;
  if (b < 512) {
    int x = b & 7, s = b >> 3;
    do_gate(P, p, x + 8 * (s & 3), s >> 2, smem);
  } else if (b < 576) {
    int i = b - 512;
    int vb = 2 * (i & 7) + 16 * ((i >> 3) & 3) + (i >> 5);
    do_v(P, p, vb, smem);
  } else {
    do_target(P, p, smem);
  }
}

// ---------------------------------------------------------------------------
// Prep kernels.
// ---------------------------------------------------------------------------
__global__ __launch_bounds__(256) void init_state(
    const float* __restrict__ others0, const float* __restrict__ target0,
    const float* __restrict__ w_ih, const float* __restrict__ b_ih,
    const float* __restrict__ b_hh,
    float* __restrict__ co, __bf16* __restrict__ A0, float* __restrict__ ht0,
    float* __restrict__ ct, unsigned int* __restrict__ cnt)
{
  int g = blockIdx.x * 256 + threadIdx.x;
  if (g == 0) *cnt = 0u;
  if (g >= 4097 * 512) return;
  int r = g >> 9, j = g & 511;
  float x0, x1;
  if (r < 4096) { x0 = others0[2 * r]; x1 = others0[2 * r + 1]; }
  else          { x0 = target0[0];     x1 = target0[1]; }
  float pre[4];
#pragma unroll
  for (int gg = 0; gg < 4; ++gg) {
    int n = gg * 512 + j;
    pre[gg] = b_ih[n] + b_hh[n] + w_ih[2 * n] * x0 + w_ih[2 * n + 1] * x1;
  }
  float cn = sigm(pre[0]) * tanh_f(pre[2]);
  float h  = sigm(pre[3]) * tanh_f(cn);
  if (r < 4096) { co[g] = cn; A0[g] = (__bf16)h; }
  else          { ct[j] = cn; ht0[j] = h; }
}

__global__ __launch_bounds__(256) void qm_init(SP P)
{
  __shared__ float qs[512];
  __shared__ float red[256];
  const int t = threadIdx.x;
  const float* h0 = P.ht;
  float q0 = P.bq[t], q1 = P.bq[t + 256];
  for (int i = 0; i < 512; ++i) {
    float h = h0[i];
    q0 += h * (float)(*(const __bf16*)&P.wqT[i * 512 + t]);
    q1 += h * (float)(*(const __bf16*)&P.wqT[i * 512 + t + 256]);
  }
  qs[t] = q0; qs[t + 256] = q1;
  red[t] = q0 * P.bk[t] + q1 * P.bk[t + 256];
  __syncthreads();
  float m0 = 0.f, m1 = 0.f;
  for (int j = 0; j < 512; ++j) {
    float qq = qs[j];
    m0 += qq * (float)(*(const __bf16*)&P.wkB[j * 512 + t]);
    m1 += qq * (float)(*(const __bf16*)&P.wkB[j * 512 + t + 256]);
  }
  P.m0[t] = m0; P.m0[t + 256] = m1;
  for (int st = 128; st > 0; st >>= 1) {
    if (t < st) red[t] += red[t + st];
    __syncthreads();
  }
  if (t == 0) P.m0[512] = red[0];
}

// 160 ntg: gates (interleaved) 0..127, wv 128..159.
__global__ __launch_bounds__(256) void pack_w(
    const float* __restrict__ w_hh, const float* __restrict__ wv,
    __bf16* __restrict__ Wp)
{
  int o = blockIdx.x * 256 + threadIdx.x;   // 1,310,720
  int j = o & 7, nn = (o >> 3) & 15, kg = (o >> 7) & 63, ntg = o >> 13;
  int n = ntg * 16 + nn, k = kg * 8 + j;
  float v;
  if (n < 2048) { int u = n >> 2, g = n & 3; v = w_hh[(g * 512 + u) * 512 + k]; }
  else          v = wv[(n - 2048) * 512 + k];
  Wp[o] = (__bf16)v;
}

__global__ __launch_bounds__(256) void pack_qk(
    const float* __restrict__ wq, const float* __restrict__ wk,
    __bf16* __restrict__ wqT, __bf16* __restrict__ wkB)
{
  int o = blockIdx.x * 256 + threadIdx.x;   // 262144
  int i = o >> 9, j = o & 511;
  wqT[o] = (__bf16)wq[j * 512 + i];
  wkB[o] = (__bf16)wk[o];
}

__global__ __launch_bounds__(256) void pack_misc(
    const float* __restrict__ b_ih, const float* __restrict__ b_hh,
    const float* __restrict__ w_ih,
    float* __restrict__ bs, float* __restrict__ w0, float* __restrict__ w1)
{
  int i = blockIdx.x * 256 + threadIdx.x;
  if (i < 2048) {
    int u = i >> 2, g = i & 3, n = g * 512 + u;
    bs[i] = b_ih[n] + b_hh[n];
    w0[i] = w_ih[2 * n];
    w1[i] = w_ih[2 * n + 1];
  }
}

__global__ __launch_bounds__(256) void scene1_kernel(
    const int* __restrict__ map, const float* __restrict__ emb,
    const float* __restrict__ w1, const float* __restrict__ b1,
    float* __restrict__ out1)
{
  __shared__ float wl[576];
  __shared__ float bl[16];
  const int t = threadIdx.x;
  for (int i = t; i < 576; i += 256) wl[i] = w1[i];
  if (t < 16) bl[t] = b1[t];
  __syncthreads();
  const int y = blockIdx.x, x = t;
  float nb[4][9];
#pragma unroll
  for (int dy = 0; dy < 3; ++dy)
#pragma unroll
    for (int dx = 0; dx < 3; ++dx) {
      int yy = y + dy - 1, xx = x + dx - 1;
      bool ok = (yy >= 0 && yy < 256 && xx >= 0 && xx < 256);
      int m = ok ? map[yy * 256 + xx] : 0;
#pragma unroll
      for (int c = 0; c < 4; ++c)
        nb[c][dy * 3 + dx] = ok ? emb[m * 4 + c] : 0.f;
    }
  for (int oc = 0; oc < 16; ++oc) {
    float a = bl[oc];
#pragma unroll
    for (int c = 0; c < 4; ++c)
#pragma unroll
      for (int k = 0; k < 9; ++k) a += wl[(oc * 4 + c) * 9 + k] * nb[c][k];
    out1[oc * 65536 + y * 256 + x] = fmaxf(a, 0.f);
  }
}

__global__ __launch_bounds__(256) void scene2_kernel(
    const float* __restrict__ out1, const float* __restrict__ w2,
    const float* __restrict__ b2, float* __restrict__ rowpart)
{
  __shared__ float wl[1152];
  __shared__ float lds4[4 * 8];
  const int t = threadIdx.x;
  const int y = blockIdx.x & 255, ocg = blockIdx.x >> 8;
  for (int i = t; i < 1152; i += 256) wl[i] = w2[ocg * 1152 + i];
  __syncthreads();
  const int x = t;
  float acc[8];
#pragma unroll
  for (int o = 0; o < 8; ++o) acc[o] = b2[ocg * 8 + o];
  for (int ic = 0; ic < 16; ++ic) {
    float nb[9];
#pragma unroll
    for (int dy = 0; dy < 3; ++dy)
#pragma unroll
      for (int dx = 0; dx < 3; ++dx) {
        int yy = y + dy - 1, xx = x + dx - 1;
        bool ok = (yy >= 0 && yy < 256 && xx >= 0 && xx < 256);
        nb[dy * 3 + dx] = ok ? out1[ic * 65536 + yy * 256 + xx] : 0.f;
      }
#pragma unroll
    for (int o = 0; o < 8; ++o) {
      const float* w = &wl[(o * 16 + ic) * 9];
#pragma unroll
      for (int k = 0; k < 9; ++k) acc[o] += w[k] * nb[k];
    }
  }
  const int wave = t >> 6, lane = t & 63;
#pragma unroll
  for (int o = 0; o < 8; ++o) {
    float v = fmaxf(acc[o], 0.f);
#pragma unroll
    for (int m = 1; m < 64; m <<= 1) v += __shfl_xor(v, m, 64);
    if (lane == 0) lds4[wave * 8 + o] = v;
  }
  __syncthreads();
  if (t < 8)
    rowpart[y * 32 + ocg * 8 + t] = lds4[t] + lds4[8 + t] + lds4[16 + t] + lds4[24 + t];
}

__global__ __launch_bounds__(512) void scene3_kernel(
    const float* __restrict__ rowpart, const float* __restrict__ fcw,
    const float* __restrict__ fcb, float* __restrict__ scene)
{
  __shared__ float mean[32];
  const int t = threadIdx.x;
  if (t < 32) {
    float s = 0.f;
    for (int y = 0; y < 256; ++y) s += rowpart[y * 32 + t];
    mean[t] = s * (1.f / 65536.f);
  }
  __syncthreads();
  float a = fcb[t];
#pragma unroll
  for (int c = 0; c < 32; ++c) a += mean[c] * fcw[t * 32 + c];
  scene[t] = a;
}

// ---------------------------------------------------------------------------
extern "C" void kernel_launch(void* const* d_in, const int* in_sizes, int n_in,
                              void* d_out, int out_size, void* d_ws, size_t ws_size,
                              hipStream_t stream) {
  const float* target    = (const float*)d_in[0];
  const float* others    = (const float*)d_in[1];
  const int*   scene_map = (const int*)d_in[2];
  const float* emb       = (const float*)d_in[3];
  const float* c1w       = (const float*)d_in[4];
  const float* c1b       = (const float*)d_in[5];
  const float* c2w       = (const float*)d_in[6];
  const float* c2b       = (const float*)d_in[7];
  const float* fcw       = (const float*)d_in[8];
  const float* fcb       = (const float*)d_in[9];
  const float* w_ih      = (const float*)d_in[10];
  const float* w_hh      = (const float*)d_in[11];
  const float* b_ih      = (const float*)d_in[12];
  const float* b_hh      = (const float*)d_in[13];
  const float* wq        = (const float*)d_in[14];
  const float* bq        = (const float*)d_in[15];
  const float* wk        = (const float*)d_in[16];
  const float* bk        = (const float*)d_in[17];
  const float* wv        = (const float*)d_in[18];
  const float* bv        = (const float*)d_in[19];
  const float* out_w     = (const float*)d_in[20];
  const float* out_b     = (const float*)d_in[21];
  float* out = (float*)d_out;

  char* ws = (char*)d_ws;
  size_t off = 0;
  auto alloc = [&](size_t bytes) { size_t o = off; off += (bytes + 255) & ~(size_t)255; return o; };
  __bf16* Wp    = (__bf16*)(ws + alloc((size_t)1310720 * 2));
  __bf16* A0    = (__bf16*)(ws + alloc((size_t)4096 * 512 * 2));
  __bf16* A1    = (__bf16*)(ws + alloc((size_t)4096 * 512 * 2));
  float*  co    = (float*)(ws + alloc((size_t)4096 * 512 * 4));
  float*  ct    = (float*)(ws + alloc(512 * 4));
  float*  ht    = (float*)(ws + alloc((size_t)65 * 512 * 4));
  __bf16* wqT   = (__bf16*)(ws + alloc((size_t)262144 * 2));
  __bf16* wkB   = (__bf16*)(ws + alloc((size_t)262144 * 2));
  float*  scene = (float*)(ws + alloc(2048));
  float*  part  = (float*)(ws + alloc(64 * 520 * 4));
  unsigned int* cnt = (unsigned int*)(ws + alloc(256));
  float*  bs    = (float*)(ws + alloc(2048 * 4));
  float*  w0p   = (float*)(ws + alloc(2048 * 4));
  float*  w1p   = (float*)(ws + alloc(2048 * 4));
  float*  m0    = (float*)(ws + alloc(513 * 4));
  float*  m1    = (float*)(ws + alloc(513 * 4));
  float*  out1  = (float*)(ws + alloc((size_t)16 * 65536 * 4));
  float*  rowp  = (float*)(ws + alloc(256 * 32 * 4));

  pack_w<<<5120, 256, 0, stream>>>(w_hh, wv, Wp);
  pack_qk<<<1024, 256, 0, stream>>>(wq, wk, wqT, wkB);
  pack_misc<<<8, 256, 0, stream>>>(b_ih, b_hh, w_ih, bs, w0p, w1p);
  scene1_kernel<<<256, 256, 0, stream>>>(scene_map, emb, c1w, c1b, out1);
  scene2_kernel<<<1024, 256, 0, stream>>>(out1, c2w, c2b, rowp);
  scene3_kernel<<<1, 512, 0, stream>>>(rowp, fcw, fcb, scene);
  init_state<<<8194, 256, 0, stream>>>(others, target, w_ih, b_ih, b_hh,
                                       co, A0, ht, ct, cnt);

  SP hp;
  hp.Wp = (const unsigned short*)Wp;
  hp.A0 = (unsigned short*)A0; hp.A1 = (unsigned short*)A1;
  hp.co = co; hp.ct = ct; hp.ht = ht;
  hp.bs4 = (const float4*)bs; hp.w04 = (const float4*)w0p; hp.w14 = (const float4*)w1p;
  hp.wqT = (const unsigned short*)wqT; hp.wkB = (const unsigned short*)wkB;
  hp.bq = bq; hp.bk = bk; hp.bv = bv;
  hp.others = others; hp.target = target;
  hp.scene = scene; hp.out_w = out_w; hp.out_b = out_b;
  hp.part = part; hp.cnt = cnt;
  hp.out = out;
  hp.m0 = m0; hp.m1 = m1;

  qm_init<<<1, 256, 0, stream>>>(hp);

  for (int p = 0; p < 64; ++p)
    step_kernel<<<577, 256, 0, stream>>>(hp, p);
}

// Round 10
// 2761.996 us; speedup vs baseline: 3.0431x; 3.0431x over previous
//
#include <hip/hip_runtime.h>
#include <hip/hip_bf16.h>

// ---------------------------------------------------------------------------
// Sophie on MI355X, round 10 = R6 (best: 2950us) + bf16 k/v Z (bias folded)
// + fp32 q vector. Everything else identical to R6: 128x256 tiles, 464-block
// step dispatch with att(p-1) merged, XCD-affine mapping, fused LSTM epilogue.
// ---------------------------------------------------------------------------

typedef __bf16 bf16x8 __attribute__((ext_vector_type(8)));
typedef float  f32x4  __attribute__((ext_vector_type(4)));

#define KD 512

__device__ __forceinline__ void gl_lds16(const void* g, void* l) {
  __builtin_amdgcn_global_load_lds(
      (const __attribute__((address_space(1))) void*)g,
      (__attribute__((address_space(3))) void*)l, 16, 0, 0);
}
__device__ __forceinline__ float sigm(float x) {
  return __builtin_amdgcn_rcpf(1.f + __expf(-x));
}
__device__ __forceinline__ float tanh_f(float x) {
  return 2.f * __builtin_amdgcn_rcpf(1.f + __expf(-2.f * x)) - 1.f;
}
__device__ __forceinline__ float sel4(f32x4 v, int i) {
  float a = (i & 1) ? v[1] : v[0];
  float b = (i & 1) ? v[3] : v[2];
  return (i & 2) ? b : a;
}
__device__ __forceinline__ float pick(int m, float o0, float o1, float o2, float o3) {
  float a = (m & 1) ? o1 : o0;
  float b = (m & 1) ? o3 : o2;
  return (m & 2) ? b : a;
}

struct SP {
  const unsigned short* Wp;        // [224 ntg][64 kg][16 nn][8 j]: gates|wk|wv|wq
  unsigned short* A0; unsigned short* A1;
  __bf16* Zb0; __bf16* Zb1;        // [4096][1024] bf16: k|v, bias folded
  float* q0; float* q1;            // [512] fp32 q (bias folded), row 4096
  float* co; float* ht;            // co[4224*512]; ht[65][512]
  const float* biasz;              // [1536] = bk|bv|bq
  const float4* bs4; const float4* w04; const float4* w14;
  const float* others; const float* target;
  const float* scene; const float* out_w; const float* out_b;
  float* part; unsigned int* cnt;
  float* out;
};

// ---------------------------------------------------------------------------
// One 128x256 GEMM tile for step p + fused epilogue (identical to R6 except
// the bn>=8 epilogues store bf16 k/v or fp32 q instead of fp32 Z).
// bn 0..7: gate cols -> LSTM. bn 8..11: k|v -> Zb bf16. bn 12..13: q -> qv.
// ---------------------------------------------------------------------------
__device__ void do_gemm(const SP& P, int p, int bm, int bn)
{
  __shared__ __align__(16) char aLds[2][128 * 64 * 2];   // 32 KB

  const int tid = threadIdx.x, wave = tid >> 6, lane = tid & 63;
  const unsigned short* A = (p & 1) ? P.A1 : P.A0;
  __bf16* An = (__bf16*)((p & 1) ? P.A0 : P.A1);
  __bf16* Zb = (p & 1) ? P.Zb1 : P.Zb0;
  float* qv  = (p & 1) ? P.q1 : P.q0;
  const int tin = (p + 1 < 31) ? (p + 1) : 31;
  const int tc  = (p + 1 < 63) ? (p + 1) : 63;
  const float* op = P.others + (size_t)tin * 8192;
  const float* tp = P.target + tc * 2;
  float* htn = P.ht + (size_t)(p + 1) * 512;

  const int m0 = bm * 128;
  const int l15 = lane & 15, lq = lane >> 4;

  int aRow[4], aOff[4], ldsOff[4];
#pragma unroll
  for (int j = 0; j < 4; ++j) {
    int chunk = j * 4 + wave;
    int r = chunk * 8 + (lane >> 3), ch = lane & 7;
    aRow[j]   = m0 + r;
    aOff[j]   = (ch ^ (r & 7)) * 8;
    ldsOff[j] = chunk * 1024;
  }
  const unsigned short* bBase =
      P.Wp + (size_t)(bn * 16 + wave * 4) * 8192 + lq * 128 + l15 * 8;

  f32x4 acc[8][4];
#pragma unroll
  for (int i = 0; i < 8; ++i)
#pragma unroll
    for (int j = 0; j < 4; ++j) acc[i][j] = f32x4{0.f, 0.f, 0.f, 0.f};

#pragma unroll
  for (int j = 0; j < 4; ++j)
    gl_lds16(A + (size_t)aRow[j] * KD + aOff[j], aLds[0] + ldsOff[j]);
  __syncthreads();

  for (int it = 0; it < 8; ++it) {
    if (it < 7) {
      const int k1 = (it + 1) * 64;
#pragma unroll
      for (int j = 0; j < 4; ++j)
        gl_lds16(A + (size_t)aRow[j] * KD + k1 + aOff[j],
                 aLds[(it + 1) & 1] + ldsOff[j]);
    }
    const char* buf = aLds[it & 1];
#pragma unroll
    for (int c = 0; c < 2; ++c) {
      bf16x8 bC[4];
#pragma unroll
      for (int nt = 0; nt < 4; ++nt)
        bC[nt] = *(const bf16x8*)(bBase + nt * 8192 + it * 1024 + c * 512);
      bf16x8 af[8];
#pragma unroll
      for (int mt = 0; mt < 8; ++mt) {
        int row = mt * 16 + l15;
        int ch16 = (c * 4 + lq) ^ (row & 7);
        af[mt] = *(const bf16x8*)(buf + row * 128 + ch16 * 16);
      }
#pragma unroll
      for (int mt = 0; mt < 8; ++mt)
#pragma unroll
        for (int nt = 0; nt < 4; ++nt)
          acc[mt][nt] = __builtin_amdgcn_mfma_f32_16x16x32_bf16(
              af[mt], bC[nt], acc[mt][nt], 0, 0, 0);
    }
    __syncthreads();
  }

  const int rq = lq * 4;

  if (bn >= 12) {
    // ---- q epilogue: row 4096 only (bm==32 tiles) ----
    if (lq == 0) {
#pragma unroll
      for (int nt = 0; nt < 4; ++nt) {
        int qcol = (bn - 12) * 256 + wave * 64 + nt * 16 + l15;
        qv[qcol] = acc[0][nt][0] + P.biasz[1024 + qcol];
      }
    }
    return;
  }

  if (bn >= 8) {
    // ---- k/v epilogue: bf16 with bias folded (rows < 4096) ----
#pragma unroll
    for (int nt = 0; nt < 4; ++nt) {
      int zcol = (bn - 8) * 256 + wave * 64 + nt * 16 + l15;   // 0..1023
      float bias = P.biasz[zcol];
#pragma unroll
      for (int mt = 0; mt < 8; ++mt) {
        int rowb = m0 + mt * 16 + rq;
#pragma unroll
        for (int r = 0; r < 4; ++r)
          Zb[(size_t)(rowb + r) * 1024 + zcol] = (__bf16)(acc[mt][nt][r] + bias);
      }
    }
    return;
  }

  // ---- gate epilogue: fused LSTM cell ----
  const int rho = lane & 3, usel = (lane >> 2) & 3;
  const int u0 = bn * 64 + wave * 16;
  float4 bsv[4], w0v[4], w1v[4];
  int uu[4];
#pragma unroll
  for (int nt = 0; nt < 4; ++nt) {
    uu[nt]  = u0 + nt * 4 + usel;
    bsv[nt] = P.bs4[uu[nt]];
    w0v[nt] = P.w04[uu[nt]];
    w1v[nt] = P.w14[uu[nt]];
  }
#pragma unroll
  for (int mt = 0; mt < 8; ++mt) {
    int row = m0 + mt * 16 + rq + rho;
    bool act = row <= 4096;
    float x0 = 0.f, x1 = 0.f;
    if (act) {
      if (row < 4096) { x0 = op[2 * row]; x1 = op[2 * row + 1]; }
      else            { x0 = tp[0];       x1 = tp[1]; }
    }
#pragma unroll
    for (int nt = 0; nt < 4; ++nt) {
      f32x4 v = acc[mt][nt];
      float own = sel4(v, rho);
      float r1  = __shfl_xor(sel4(v, rho ^ 1), 1, 64);
      float r2  = __shfl_xor(sel4(v, rho ^ 2), 2, 64);
      float r3  = __shfl_xor(sel4(v, rho ^ 3), 3, 64);
      float g0 = pick(rho,     own, r1, r2, r3);
      float g1 = pick(rho ^ 1, own, r1, r2, r3);
      float g2 = pick(rho ^ 2, own, r1, r2, r3);
      float g3 = pick(rho ^ 3, own, r1, r2, r3);
      if (act) {
        float4 bs = bsv[nt], w0 = w0v[nt], w1 = w1v[nt];
        float p0 = g0 + bs.x + w0.x * x0 + w1.x * x1;
        float p1 = g1 + bs.y + w0.y * x0 + w1.y * x1;
        float p2 = g2 + bs.z + w0.z * x0 + w1.z * x1;
        float p3 = g3 + bs.w + w0.w * x0 + w1.w * x1;
        int u = uu[nt];
        size_t ci = (size_t)row * 512 + u;
        float c_old = P.co[ci];
        float ii = sigm(p0), ff = sigm(p1), gg = tanh_f(p2), oo = sigm(p3);
        float cn = ff * c_old + ii * gg;
        float h  = oo * tanh_f(cn);
        P.co[ci] = cn;
        An[ci] = (__bf16)h;
        if (row == 4096) htn[u] = h;
      }
    }
  }
}

// ---------------------------------------------------------------------------
// Attention for step p, task b (64 tasks x 64 rows) + last-done finalize.
// Zb bf16 (bias folded), qv fp32.
// ---------------------------------------------------------------------------
__device__ void do_att(const SP& P, int p, int b)
{
  __shared__ __align__(16) float qs[512];
  __shared__ float red[256];
  __shared__ float red2[256];
  __shared__ float es[64];
  __shared__ unsigned int sOld;
  const int t = threadIdx.x;
  const __bf16* Zb = (p & 1) ? P.Zb1 : P.Zb0;
  const float* qv  = (p & 1) ? P.q1 : P.q0;
  const float* ht  = P.ht + (size_t)p * 512;

  for (int c = t; c < 512; c += 256) qs[c] = qv[c];
  __syncthreads();

  const int r0 = b * 64, rl = t >> 2, p4 = t & 3;
  const bf16x8* krow = (const bf16x8*)(Zb + (size_t)(r0 + rl) * 1024);
  float a = 0.f;
  for (int i = p4; i < 64; i += 4) {
    bf16x8 kk = krow[i];
    const float* qq = qs + i * 8;
#pragma unroll
    for (int j = 0; j < 8; ++j) a += (float)kk[j] * qq[j];
  }
  red[t] = a;
  __syncthreads();
  if (t < 64)
    es[t] = __expf((red[4 * t] + red[4 * t + 1] + red[4 * t + 2] + red[4 * t + 3]) *
                   0.04419417382415922f);
  __syncthreads();

  float s0 = 0.f, s1 = 0.f;
  for (int r = 0; r < 64; ++r) {
    const __bf16* vr = Zb + (size_t)(r0 + r) * 1024 + 512;
    float e = es[r];
    s0 += e * (float)vr[t];
    s1 += e * (float)vr[t + 256];
  }
  P.part[b * 513 + t] = s0;
  P.part[b * 513 + 256 + t] = s1;
  if (t == 0) {
    float se = 0.f;
#pragma unroll
    for (int r = 0; r < 64; ++r) se += es[r];
    P.part[b * 513 + 512] = se;
  }
  __threadfence();
  __syncthreads();
  if (t == 0) sOld = atomicAdd(P.cnt, 1u);
  __syncthreads();
  if (sOld == 63) {
    __threadfence();
    float s = 0.f, s2 = 0.f, se = 0.f;
    for (int bb = 0; bb < 64; ++bb) {
      s  += P.part[bb * 513 + t];
      s2 += P.part[bb * 513 + 256 + t];
      se += P.part[bb * 513 + 512];
    }
    float inv = 1.f / se;
    float va = ht[t] + s * inv + P.scene[t];
    float vb = ht[t + 256] + s2 * inv + P.scene[t + 256];
    red[t]  = va * P.out_w[t]       + vb * P.out_w[t + 256];
    red2[t] = va * P.out_w[512 + t] + vb * P.out_w[768 + t];
    __syncthreads();
    for (int st = 128; st > 0; st >>= 1) {
      if (t < st) { red[t] += red[t + st]; red2[t] += red2[t + st]; }
      __syncthreads();
    }
    if (t == 0) {
      P.out[2 * p]     = red[0]  + P.out_b[0];
      P.out[2 * p + 1] = red2[0] + P.out_b[1];
      *P.cnt = 0;
    }
  }
}

// ---------------------------------------------------------------------------
// Step dispatch: 464 blocks (identical decode to R6).
// ---------------------------------------------------------------------------
__global__ __launch_bounds__(256, 2) void step_kernel(SP P, int p)
{
  const int b = blockIdx.x, x = b & 7, s = b >> 3;
  if (x == 0 && s >= 48) {
    int ti = s - 48;                       // 0..9
    int bn = (ti < 8) ? ti : (12 + (ti - 8));
    do_gemm(P, p, 32, bn);
  } else if (s < 48) {
    int bm = x + 8 * (s / 12);
    int ti = s % 12;
    do_gemm(P, p, bm, ti);                 // bn = ti (0..11)
  } else {
    int a = (x - 1) + 7 * (s - 48);
    if (a < 64 && p >= 1) do_att(P, p - 1, a);
  }
}

__global__ __launch_bounds__(256) void att_step(SP P, int p) {
  do_att(P, p, blockIdx.x);
}

// ---------------------------------------------------------------------------
// Prep kernels (verified in R6).
// ---------------------------------------------------------------------------
__global__ __launch_bounds__(256) void init_state(
    const float* __restrict__ others0, const float* __restrict__ target0,
    const float* __restrict__ w_ih, const float* __restrict__ b_ih,
    const float* __restrict__ b_hh,
    float* __restrict__ co, __bf16* __restrict__ A0, float* __restrict__ ht0,
    unsigned int* __restrict__ cnt)
{
  int g = blockIdx.x * 256 + threadIdx.x;
  if (g == 0) *cnt = 0u;
  if (g >= 4097 * 512) return;
  int r = g >> 9, j = g & 511;
  float x0, x1;
  if (r < 4096) { x0 = others0[2 * r]; x1 = others0[2 * r + 1]; }
  else          { x0 = target0[0];     x1 = target0[1]; }
  float pre[4];
#pragma unroll
  for (int gg = 0; gg < 4; ++gg) {
    int n = gg * 512 + j;
    pre[gg] = b_ih[n] + b_hh[n] + w_ih[2 * n] * x0 + w_ih[2 * n + 1] * x1;
  }
  float cn = sigm(pre[0]) * tanh_f(pre[2]);
  float h  = sigm(pre[3]) * tanh_f(cn);
  co[g] = cn;
  A0[g] = (__bf16)h;
  if (r == 4096) ht0[j] = h;
}

__global__ __launch_bounds__(256) void pack_w(
    const float* __restrict__ w_hh, const float* __restrict__ wk,
    const float* __restrict__ wv,   const float* __restrict__ wq,
    __bf16* __restrict__ Wp)
{
  int o = blockIdx.x * 256 + threadIdx.x;   // 224*8192 = 1,835,008
  int j = o & 7, nn = (o >> 3) & 15, kg = (o >> 7) & 63, ntg = o >> 13;
  int n = ntg * 16 + nn, k = kg * 8 + j;
  float v;
  if (n < 2048)      { int u = n >> 2, g = n & 3; v = w_hh[(g * 512 + u) * 512 + k]; }
  else if (n < 2560) v = wk[(n - 2048) * 512 + k];
  else if (n < 3072) v = wv[(n - 2560) * 512 + k];
  else               v = wq[(n - 3072) * 512 + k];
  Wp[o] = (__bf16)v;
}

__global__ __launch_bounds__(256) void pack_misc(
    const float* __restrict__ b_ih, const float* __restrict__ b_hh,
    const float* __restrict__ w_ih,
    const float* __restrict__ bk, const float* __restrict__ bv,
    const float* __restrict__ bq,
    float* __restrict__ bs, float* __restrict__ w0, float* __restrict__ w1,
    float* __restrict__ biasz)
{
  int i = blockIdx.x * 256 + threadIdx.x;
  if (i < 2048) {
    int u = i >> 2, g = i & 3, n = g * 512 + u;
    bs[i] = b_ih[n] + b_hh[n];
    w0[i] = w_ih[2 * n];
    w1[i] = w_ih[2 * n + 1];
  } else if (i < 2048 + 1536) {
    int z = i - 2048;
    biasz[z] = (z < 512) ? bk[z] : (z < 1024 ? bv[z - 512] : bq[z - 1024]);
  }
}

__global__ __launch_bounds__(256) void scene1_kernel(
    const int* __restrict__ map, const float* __restrict__ emb,
    const float* __restrict__ w1, const float* __restrict__ b1,
    float* __restrict__ out1)
{
  __shared__ float wl[576];
  __shared__ float bl[16];
  const int t = threadIdx.x;
  for (int i = t; i < 576; i += 256) wl[i] = w1[i];
  if (t < 16) bl[t] = b1[t];
  __syncthreads();
  const int y = blockIdx.x, x = t;
  float nb[4][9];
#pragma unroll
  for (int dy = 0; dy < 3; ++dy)
#pragma unroll
    for (int dx = 0; dx < 3; ++dx) {
      int yy = y + dy - 1, xx = x + dx - 1;
      bool ok = (yy >= 0 && yy < 256 && xx >= 0 && xx < 256);
      int m = ok ? map[yy * 256 + xx] : 0;
#pragma unroll
      for (int c = 0; c < 4; ++c)
        nb[c][dy * 3 + dx] = ok ? emb[m * 4 + c] : 0.f;
    }
  for (int oc = 0; oc < 16; ++oc) {
    float a = bl[oc];
#pragma unroll
    for (int c = 0; c < 4; ++c)
#pragma unroll
      for (int k = 0; k < 9; ++k) a += wl[(oc * 4 + c) * 9 + k] * nb[c][k];
    out1[oc * 65536 + y * 256 + x] = fmaxf(a, 0.f);
  }
}

__global__ __launch_bounds__(256) void scene2_kernel(
    const float* __restrict__ out1, const float* __restrict__ w2,
    const float* __restrict__ b2, float* __restrict__ rowpart)
{
  __shared__ float wl[1152];
  __shared__ float lds4[4 * 8];
  const int t = threadIdx.x;
  const int y = blockIdx.x & 255, ocg = blockIdx.x >> 8;
  for (int i = t; i < 1152; i += 256) wl[i] = w2[ocg * 1152 + i];
  __syncthreads();
  const int x = t;
  float acc[8];
#pragma unroll
  for (int o = 0; o < 8; ++o) acc[o] = b2[ocg * 8 + o];
  for (int ic = 0; ic < 16; ++ic) {
    float nb[9];
#pragma unroll
    for (int dy = 0; dy < 3; ++dy)
#pragma unroll
      for (int dx = 0; dx < 3; ++dx) {
        int yy = y + dy - 1, xx = x + dx - 1;
        bool ok = (yy >= 0 && yy < 256 && xx >= 0 && xx < 256);
        nb[dy * 3 + dx] = ok ? out1[ic * 65536 + yy * 256 + xx] : 0.f;
      }
#pragma unroll
    for (int o = 0; o < 8; ++o) {
      const float* w = &wl[(o * 16 + ic) * 9];
#pragma unroll
      for (int k = 0; k < 9; ++k) acc[o] += w[k] * nb[k];
    }
  }
  const int wave = t >> 6, lane = t & 63;
#pragma unroll
  for (int o = 0; o < 8; ++o) {
    float v = fmaxf(acc[o], 0.f);
#pragma unroll
    for (int m = 1; m < 64; m <<= 1) v += __shfl_xor(v, m, 64);
    if (lane == 0) lds4[wave * 8 + o] = v;
  }
  __syncthreads();
  if (t < 8)
    rowpart[y * 32 + ocg * 8 + t] = lds4[t] + lds4[8 + t] + lds4[16 + t] + lds4[24 + t];
}

__global__ __launch_bounds__(512) void scene3_kernel(
    const float* __restrict__ rowpart, const float* __restrict__ fcw,
    const float* __restrict__ fcb, float* __restrict__ scene)
{
  __shared__ float mean[32];
  const int t = threadIdx.x;
  if (t < 32) {
    float s = 0.f;
    for (int y = 0; y < 256; ++y) s += rowpart[y * 32 + t];
    mean[t] = s * (1.f / 65536.f);
  }
  __syncthreads();
  float a = fcb[t];
#pragma unroll
  for (int c = 0; c < 32; ++c) a += mean[c] * fcw[t * 32 + c];
  scene[t] = a;
}

// ---------------------------------------------------------------------------
extern "C" void kernel_launch(void* const* d_in, const int* in_sizes, int n_in,
                              void* d_out, int out_size, void* d_ws, size_t ws_size,
                              hipStream_t stream) {
  const float* target    = (const float*)d_in[0];
  const float* others    = (const float*)d_in[1];
  const int*   scene_map = (const int*)d_in[2];
  const float* emb       = (const float*)d_in[3];
  const float* c1w       = (const float*)d_in[4];
  const float* c1b       = (const float*)d_in[5];
  const float* c2w       = (const float*)d_in[6];
  const float* c2b       = (const float*)d_in[7];
  const float* fcw       = (const float*)d_in[8];
  const float* fcb       = (const float*)d_in[9];
  const float* w_ih      = (const float*)d_in[10];
  const float* w_hh      = (const float*)d_in[11];
  const float* b_ih      = (const float*)d_in[12];
  const float* b_hh      = (const float*)d_in[13];
  const float* wq        = (const float*)d_in[14];
  const float* bq        = (const float*)d_in[15];
  const float* wk        = (const float*)d_in[16];
  const float* bk        = (const float*)d_in[17];
  const float* wv        = (const float*)d_in[18];
  const float* bv        = (const float*)d_in[19];
  const float* out_w     = (const float*)d_in[20];
  const float* out_b     = (const float*)d_in[21];
  float* out = (float*)d_out;

  char* ws = (char*)d_ws;
  size_t off = 0;
  auto alloc = [&](size_t bytes) { size_t o = off; off += (bytes + 255) & ~(size_t)255; return o; };
  __bf16* Zb0   = (__bf16*)(ws + alloc((size_t)4096 * 1024 * 2));  // 8.39 MB
  __bf16* Zb1   = (__bf16*)(ws + alloc((size_t)4096 * 1024 * 2));
  float*  q0    = (float*)(ws + alloc(512 * 4));
  float*  q1    = (float*)(ws + alloc(512 * 4));
  __bf16* Wp    = (__bf16*)(ws + alloc((size_t)1835008 * 2));
  __bf16* A0    = (__bf16*)(ws + alloc((size_t)4224 * 512 * 2));
  __bf16* A1    = (__bf16*)(ws + alloc((size_t)4224 * 512 * 2));
  float*  co    = (float*)(ws + alloc((size_t)4097 * 512 * 4));
  float*  ht    = (float*)(ws + alloc((size_t)65 * 512 * 4));
  float*  scene = (float*)(ws + alloc(2048));
  float*  part  = (float*)(ws + alloc(64 * 513 * 4));
  unsigned int* cnt = (unsigned int*)(ws + alloc(256));
  float*  bs    = (float*)(ws + alloc(2048 * 4));
  float*  w0p   = (float*)(ws + alloc(2048 * 4));
  float*  w1p   = (float*)(ws + alloc(2048 * 4));
  float*  biasz = (float*)(ws + alloc(1536 * 4));
  float*  out1  = (float*)(ws + alloc((size_t)16 * 65536 * 4));
  float*  rowp  = (float*)(ws + alloc(256 * 32 * 4));

  pack_w<<<7168, 256, 0, stream>>>(w_hh, wk, wv, wq, Wp);
  pack_misc<<<14, 256, 0, stream>>>(b_ih, b_hh, w_ih, bk, bv, bq, bs, w0p, w1p, biasz);
  scene1_kernel<<<256, 256, 0, stream>>>(scene_map, emb, c1w, c1b, out1);
  scene2_kernel<<<1024, 256, 0, stream>>>(out1, c2w, c2b, rowp);
  scene3_kernel<<<1, 512, 0, stream>>>(rowp, fcw, fcb, scene);
  init_state<<<8194, 256, 0, stream>>>(others, target, w_ih, b_ih, b_hh, co, A0, ht, cnt);

  SP hp;
  hp.Wp = (const unsigned short*)Wp;
  hp.A0 = (unsigned short*)A0; hp.A1 = (unsigned short*)A1;
  hp.Zb0 = Zb0; hp.Zb1 = Zb1;
  hp.q0 = q0; hp.q1 = q1;
  hp.co = co; hp.ht = ht;
  hp.biasz = biasz;
  hp.bs4 = (const float4*)bs; hp.w04 = (const float4*)w0p; hp.w14 = (const float4*)w1p;
  hp.others = others; hp.target = target;
  hp.scene = scene; hp.out_w = out_w; hp.out_b = out_b;
  hp.part = part; hp.cnt = cnt;
  hp.out = out;

  for (int p = 0; p < 64; ++p)
    step_kernel<<<464, 256, 0, stream>>>(hp, p);
  att_step<<<64, 256, 0, stream>>>(hp, 63);
}